// Round 4
// baseline (395.602 us; speedup 1.0000x reference)
//
#include <hip/hip_runtime.h>
#include <hip/hip_bf16.h>
#include <math.h>

#define BB 8
#define CCH 256
#define HWN 4096
#define RR 16
#define PJ 72   // p_lds ushort row stride: 144B rows, 16B-aligned

typedef __attribute__((ext_vector_type(8))) short short8;   // 8 bf16 = K=32 MFMA A/B frag
typedef __attribute__((ext_vector_type(4))) float f32x4;    // MFMA C/D frag

static __device__ __forceinline__ unsigned short f2bf(float x) {
    union { float f; unsigned u; } v; v.f = x;
    return (unsigned short)((v.u + 0x8000u) >> 16);   // round-half-up bf16
}

// ---------------- K1: avg+max pool over spatial, per (b,c) ----------------
__global__ __launch_bounds__(256) void k_pool(const float* __restrict__ x,
                                              float* __restrict__ avgp,
                                              float* __restrict__ maxp) {
    int bc = blockIdx.x;
    const float4* p = (const float4*)(x + (size_t)bc * HWN);
    int t = threadIdx.x;
    float s = 0.f, m = -INFINITY;
#pragma unroll
    for (int i = 0; i < 4; ++i) {
        float4 v = p[t + 256 * i];
        s += v.x + v.y + v.z + v.w;
        m = fmaxf(m, fmaxf(fmaxf(v.x, v.y), fmaxf(v.z, v.w)));
    }
    for (int off = 32; off; off >>= 1) {
        s += __shfl_down(s, off);
        m = fmaxf(m, __shfl_down(m, off));
    }
    __shared__ float ss[4], sm[4];
    int wid = t >> 6;
    if ((t & 63) == 0) { ss[wid] = s; sm[wid] = m; }
    __syncthreads();
    if (t == 0) {
        float S = ss[0] + ss[1] + ss[2] + ss[3];
        float M = fmaxf(fmaxf(sm[0], sm[1]), fmaxf(sm[2], sm[3]));
        avgp[bc] = S * (1.f / (float)HWN);
        maxp[bc] = M;
    }
}

// ---------------- K2: SE gate ----------------
__global__ __launch_bounds__(256) void k_gate(const float* __restrict__ avgp,
                                              const float* __restrict__ maxp,
                                              const float* __restrict__ w1,
                                              const float* __restrict__ w2,
                                              float* __restrict__ gate) {
    int b = blockIdx.x, t = threadIdx.x;
    __shared__ float sa[CCH], sx[CCH], sh[32];
    sa[t] = avgp[b * CCH + t];
    sx[t] = maxp[b * CCH + t];
    __syncthreads();
    if (t < 32) {
        int r = t & 15;
        const float* src = (t < 16) ? sa : sx;
        float h = 0.f;
        for (int c = 0; c < CCH; ++c) h += w1[r * CCH + c] * src[c];
        sh[t] = fmaxf(h, 0.f);
    }
    __syncthreads();
    float g = 0.f;
#pragma unroll
    for (int r = 0; r < RR; ++r) g += w2[t * RR + r] * (sh[r] + sh[16 + r]);
    gate[b * CCH + t] = 1.f / (1.f + __expf(-g));
}

// ---------------- K-wprep: pack [vw;qw;kw] -> Wb bf16 [288][256] ----------------
__global__ __launch_bounds__(256) void k_wprep(const float* __restrict__ vw,
                                               const float* __restrict__ qw,
                                               const float* __restrict__ kw,
                                               unsigned short* __restrict__ Wb) {
    int idx = blockIdx.x * 256 + threadIdx.x;   // 288*256 = 73728
    int m = idx >> 8, c = idx & 255;
    float v;
    if (m < 256) v = vw[idx];
    else if (m < 272) v = qw[(m - 256) * 256 + c];
    else v = kw[(m - 272) * 256 + c];
    Wb[idx] = f2bf(v);
}

// ---------------- K-proj: fused q,k,v = Wb @ (x*gate) via bf16 MFMA ----------------
// XCD-swizzled: b = blk&7 so each XCD owns one batch (weights + x-slice L2-resident,
// and vB/qT/kT stay in that XCD's L2 for k_attn).
// x staged as bf16 TRANSPOSED [n][c] in LDS -> B-frag = one ds_read_b128.
__global__ __launch_bounds__(256) void k_proj(const float* __restrict__ x,
                                              const float* __restrict__ gate,
                                              const unsigned short* __restrict__ Wb,
                                              const float* __restrict__ vb,
                                              const float* __restrict__ qb,
                                              const float* __restrict__ kb,
                                              unsigned short* __restrict__ qT,
                                              unsigned short* __restrict__ kT,
                                              unsigned short* __restrict__ vB) {
    int b = blockIdx.x & 7;
    int n0 = (blockIdx.x >> 3) << 6;
    int t = threadIdx.x;
    int w = t >> 6, l = t & 63, quad = l >> 4, ln = l & 15;

    __shared__ __align__(16) unsigned short xs_t[64][PJ];  // [n_local][c_local] bf16
    __shared__ float qk_s[32][66];   // q rows 0..15, k rows 16..31 (fp32, for transpose)

    const f32x4 zf = {0.f, 0.f, 0.f, 0.f};
    f32x4 acc[18];
#pragma unroll
    for (int mt = 0; mt < 18; ++mt) acc[mt] = zf;

    for (int cc = 0; cc < 4; ++cc) {
        __syncthreads();   // previous chunk's readers done
#pragma unroll
        for (int it = 0; it < 4; ++it) {
            int idx = it * 256 + t;
            int cl = idx >> 4, nq = idx & 15;
            int c = cc * 64 + cl;
            float g = gate[b * CCH + c];
            float4 v = *(const float4*)(x + (((size_t)(b * CCH + c)) << 12) + n0 + nq * 4);
            xs_t[nq * 4 + 0][cl] = f2bf(v.x * g);
            xs_t[nq * 4 + 1][cl] = f2bf(v.y * g);
            xs_t[nq * 4 + 2][cl] = f2bf(v.z * g);
            xs_t[nq * 4 + 3][cl] = f2bf(v.w * g);
        }
        __syncthreads();

        // B-frag: B[k=kc*32+quad*8+kk][n=w*16+ln] = single b128 read
        short8 bfrag[2];
#pragma unroll
        for (int kc = 0; kc < 2; ++kc)
            bfrag[kc] = *(const short8*)&xs_t[w * 16 + ln][kc * 32 + quad * 8];

#pragma unroll
        for (int mt = 0; mt < 18; ++mt) {
#pragma unroll
            for (int kc = 0; kc < 2; ++kc) {
                short8 af = *(const short8*)(Wb + ((size_t)(mt * 16 + ln)) * 256 + cc * 64 + kc * 32 + quad * 8);
                acc[mt] = __builtin_amdgcn_mfma_f32_16x16x32_bf16(af, bfrag[kc], acc[mt], 0, 0, 0);
            }
        }
    }

    // store v rows (m-tiles 0..15): D[m=mt*16+quad*4+r][n=n0+w*16+ln]
#pragma unroll
    for (int mt = 0; mt < 16; ++mt) {
#pragma unroll
        for (int r = 0; r < 4; ++r) {
            int m = mt * 16 + quad * 4 + r;
            vB[(((size_t)(b * CCH + m)) << 12) + n0 + w * 16 + ln] = f2bf(acc[mt][r] + vb[m]);
        }
    }
    // q/k: bounce through LDS to get [n][d] layout
#pragma unroll
    for (int r = 0; r < 4; ++r) {
        qk_s[quad * 4 + r][w * 16 + ln] = acc[16][r];        // q: d = quad*4+r
        qk_s[16 + quad * 4 + r][w * 16 + ln] = acc[17][r];   // k
    }
    __syncthreads();
    if (t < 128) {
        int isK = t >> 6;
        int n = t & 63;
        const float* bias = isK ? kb : qb;
        unsigned u32[8];
#pragma unroll
        for (int j = 0; j < 8; ++j) {
            unsigned lo = f2bf(qk_s[isK * 16 + 2 * j][n] + bias[2 * j]);
            unsigned hi = f2bf(qk_s[isK * 16 + 2 * j + 1][n] + bias[2 * j + 1]);
            u32[j] = lo | (hi << 16);
        }
        unsigned short* dst = (isK ? kT : qT) + ((size_t)(b * HWN + n0 + n)) * RR;
        uint4 d0 = {u32[0], u32[1], u32[2], u32[3]};
        uint4 d1 = {u32[4], u32[5], u32[6], u32[7]};
        ((uint4*)dst)[0] = d0;
        ((uint4*)dst)[1] = d1;
    }
}

// ---------------- K-attn: MFMA flash attention, j-tile 64, P-dbuf, 1 barrier/iter,
// V+K prefetched one full iteration ahead (register dbuf), XCD-swizzled ----------------
__global__ __launch_bounds__(256) void k_attn(const unsigned short* __restrict__ qT,
                                              const unsigned short* __restrict__ kT,
                                              const unsigned short* __restrict__ vB,
                                              const float* __restrict__ x,
                                              const float* __restrict__ gate,
                                              const float* __restrict__ gamma,
                                              float* __restrict__ out) {
    int b = blockIdx.x & 7;                 // XCD swizzle: batch <-> XCD
    int i0 = ((blockIdx.x >> 3) & 63) << 6;
    int t = threadIdx.x;
    int w = t >> 6, l = t & 63;
    int quad = l >> 4, ln = l & 15;

    __shared__ __align__(16) unsigned short p_lds[2][64 * PJ];
    __shared__ float l_s[64];

    const short8 zs = {0, 0, 0, 0, 0, 0, 0, 0};
    const f32x4 zf = {0.f, 0.f, 0.f, 0.f};

    // Q A-frag (persistent): A[m=ln][k=quad*8+kk], k=d (quads 2,3 zero)
    short8 aq = zs;
    if (quad < 2)
        aq = *(const short8*)(qT + (((size_t)(b * HWN + i0 + w * 16 + ln)) << 4) + (quad << 3));

    f32x4 acc[4][4];
#pragma unroll
    for (int cs = 0; cs < 4; ++cs)
#pragma unroll
        for (int is = 0; is < 4; ++is) acc[cs][is] = zf;
    float lpart[4] = {0.f, 0.f, 0.f, 0.f};

    const float c1 = 1.44269504f;      // log2(e)
    const float c0 = -11.5415603f;     // -8*log2(e): fixed shift, cancels in p/l

    const unsigned short* vrow = vB + (((size_t)(b * CCH + w * 64)) << 12);
    const unsigned short* krow = kT + (((size_t)(b * HWN)) << 4);

    // register-dbuf operand sets (static indexing via 2x-unrolled loop)
    short8 av0[2][4], av1[2][4];   // V A-frags: [ks][cs]
    short8 bk0[4], bk1[4];         // K B-frags: [jn]
#pragma unroll
    for (int jn = 0; jn < 4; ++jn) { bk0[jn] = zs; bk1[jn] = zs; }

    // prologue: loads for jt=0
#pragma unroll
    for (int ks = 0; ks < 2; ++ks)
#pragma unroll
        for (int cs = 0; cs < 4; ++cs)
            av0[ks][cs] = *(const short8*)(vrow + (((size_t)(cs * 16 + ln)) << 12) + ks * 32 + quad * 8);
    if (quad < 2)
#pragma unroll
        for (int jn = 0; jn < 4; ++jn)
            bk0[jn] = *(const short8*)(krow + (((size_t)(jn * 16 + ln)) << 4) + (quad << 3));

    auto step = [&](short8 (&avC)[2][4], short8 (&avN)[2][4],
                    short8 (&bkC)[4], short8 (&bkN)[4],
                    unsigned short* pbuf, int j0, bool pf) {
        // prefetch NEXT iteration's V and K frags (drained at the barrier ~a full
        // iteration after issue -> latency hidden)
        if (pf) {
            int j0n = j0 + 64;
#pragma unroll
            for (int ks = 0; ks < 2; ++ks)
#pragma unroll
                for (int cs = 0; cs < 4; ++cs)
                    avN[ks][cs] = *(const short8*)(vrow + (((size_t)(cs * 16 + ln)) << 12) + j0n + ks * 32 + quad * 8);
            if (quad < 2)
#pragma unroll
                for (int jn = 0; jn < 4; ++jn)
                    bkN[jn] = *(const short8*)(krow + (((size_t)(j0n + jn * 16 + ln)) << 4) + (quad << 3));
        }

        // S = Q.K^T for this wave's 16 i x 64 j
        f32x4 sf[4];
#pragma unroll
        for (int jn = 0; jn < 4; ++jn)
            sf[jn] = __builtin_amdgcn_mfma_f32_16x16x32_bf16(aq, bkC[jn], zf, 0, 0, 0);

        // softmax (fixed shift) + P -> LDS (bf16, C/D layout rows)
#pragma unroll
        for (int jn = 0; jn < 4; ++jn)
#pragma unroll
            for (int r = 0; r < 4; ++r) {
                float p = exp2f(fmaf(sf[jn][r], c1, c0));
                lpart[r] += p;
                pbuf[(w * 16 + quad * 4 + r) * PJ + jn * 16 + ln] = f2bf(p);
            }

        __syncthreads();   // the only barrier: P(buf) visible; prefetches drained

        // PV: A = V[c][j], B = P[j][i]
#pragma unroll
        for (int ks = 0; ks < 2; ++ks) {
            short8 bp[4];
#pragma unroll
            for (int is = 0; is < 4; ++is)
                bp[is] = *(const short8*)(pbuf + (is * 16 + ln) * PJ + ks * 32 + quad * 8);
#pragma unroll
            for (int cs = 0; cs < 4; ++cs)
#pragma unroll
                for (int is = 0; is < 4; ++is)
                    acc[cs][is] = __builtin_amdgcn_mfma_f32_16x16x32_bf16(avC[ks][cs], bp[is], acc[cs][is], 0, 0, 0);
        }
        // no second barrier: next step writes the other P buffer; this buffer is
        // only rewritten after the NEXT barrier, by which time all reads are done.
    };

    for (int jt2 = 0; jt2 < 32; ++jt2) {
        step(av0, av1, bk0, bk1, &p_lds[0][0], (2 * jt2) << 6, true);
        step(av1, av0, bk1, bk0, &p_lds[1][0], (2 * jt2 + 1) << 6, jt2 < 31);
    }

    // l: butterfly over the 16 lanes of each quad
#pragma unroll
    for (int r = 0; r < 4; ++r) {
        float v = lpart[r];
        v += __shfl_xor(v, 1, 64);
        v += __shfl_xor(v, 2, 64);
        v += __shfl_xor(v, 4, 64);
        v += __shfl_xor(v, 8, 64);
        if (ln == 0) l_s[w * 16 + quad * 4 + r] = v;
    }
    __syncthreads();

    float g = gamma[0];
    float rinv[4];
#pragma unroll
    for (int is = 0; is < 4; ++is) rinv[is] = g / l_s[is * 16 + ln];

    // epilogue: out = gamma*o/l + x*gate
#pragma unroll
    for (int cs = 0; cs < 4; ++cs) {
#pragma unroll
        for (int r = 0; r < 4; ++r) {
            int c = w * 64 + cs * 16 + quad * 4 + r;
            float gc = gate[b * CCH + c];
            size_t rowoff = (((size_t)(b * CCH + c)) << 12) + i0;
            float* po = out + rowoff;
            const float* px = x + rowoff;
#pragma unroll
            for (int is = 0; is < 4; ++is) {
                int idx = is * 16 + ln;
                po[idx] = acc[cs][is][r] * rinv[is] + px[idx] * gc;
            }
        }
    }
}

extern "C" void kernel_launch(void* const* d_in, const int* in_sizes, int n_in,
                              void* d_out, int out_size, void* d_ws, size_t ws_size,
                              hipStream_t stream) {
    const float* x = (const float*)d_in[0];
    const float* w1 = (const float*)d_in[1];
    const float* w2 = (const float*)d_in[2];
    const float* qw = (const float*)d_in[3];
    const float* qb = (const float*)d_in[4];
    const float* kw = (const float*)d_in[5];
    const float* kb = (const float*)d_in[6];
    const float* vw = (const float*)d_in[7];
    const float* vb = (const float*)d_in[8];
    const float* gamma = (const float*)d_in[9];
    float* out = (float*)d_out;
    char* ws = (char*)d_ws;

    float* avgp = (float*)(ws);                        // 8 KB
    float* maxp = (float*)(ws + 8192);                 // 8 KB
    float* gate = (float*)(ws + 16384);                // 8 KB
    unsigned short* Wb = (unsigned short*)(ws + 24576);               // 147456 B [288][256] bf16
    unsigned short* qT = (unsigned short*)(ws + 24576 + 147456);      // 1 MB [b][n][16]
    unsigned short* kT = (unsigned short*)(ws + 24576 + 147456 + 1048576);
    unsigned short* vB = (unsigned short*)(ws + 24576 + 147456 + 2097152);  // 16.8 MB [b][c][n]

    k_pool<<<2048, 256, 0, stream>>>(x, avgp, maxp);
    k_wprep<<<288, 256, 0, stream>>>(vw, qw, kw, Wb);
    k_gate<<<8, 256, 0, stream>>>(avgp, maxp, w1, w2, gate);
    k_proj<<<512, 256, 0, stream>>>(x, gate, Wb, vb, qb, kb, qT, kT, vB);
    k_attn<<<512, 256, 0, stream>>>(qT, kT, vB, x, gate, gamma, out);
}

// Round 5
// 355.965 us; speedup vs baseline: 1.1114x; 1.1114x over previous
//
#include <hip/hip_runtime.h>
#include <hip/hip_bf16.h>
#include <math.h>

#define BB 8
#define CCH 256
#define HWN 4096
#define RR 16
#define PSTR 68   // p_lds ushort row stride (136B): <=4-way banks on b128 reads, ~free on b64 stores

typedef __attribute__((ext_vector_type(8))) short short8;   // 8 bf16 = K=32 MFMA A/B frag
typedef __attribute__((ext_vector_type(4))) float f32x4;    // MFMA C/D frag

static __device__ __forceinline__ unsigned short f2bf(float x) {
    union { float f; unsigned u; } v; v.f = x;
    return (unsigned short)((v.u + 0x8000u) >> 16);   // round-half-up bf16
}
static __device__ __forceinline__ unsigned bfr(float x) {   // bits + rounding offset
    union { float f; unsigned u; } v; v.f = x;
    return v.u + 0x8000u;
}

// ---------------- K1: avg+max pool over spatial, per (b,c) ----------------
__global__ __launch_bounds__(256) void k_pool(const float* __restrict__ x,
                                              float* __restrict__ avgp,
                                              float* __restrict__ maxp) {
    int bc = blockIdx.x;
    const float4* p = (const float4*)(x + (size_t)bc * HWN);
    int t = threadIdx.x;
    float s = 0.f, m = -INFINITY;
#pragma unroll
    for (int i = 0; i < 4; ++i) {
        float4 v = p[t + 256 * i];
        s += v.x + v.y + v.z + v.w;
        m = fmaxf(m, fmaxf(fmaxf(v.x, v.y), fmaxf(v.z, v.w)));
    }
    for (int off = 32; off; off >>= 1) {
        s += __shfl_down(s, off);
        m = fmaxf(m, __shfl_down(m, off));
    }
    __shared__ float ss[4], sm[4];
    int wid = t >> 6;
    if ((t & 63) == 0) { ss[wid] = s; sm[wid] = m; }
    __syncthreads();
    if (t == 0) {
        float S = ss[0] + ss[1] + ss[2] + ss[3];
        float M = fmaxf(fmaxf(sm[0], sm[1]), fmaxf(sm[2], sm[3]));
        avgp[bc] = S * (1.f / (float)HWN);
        maxp[bc] = M;
    }
}

// ---------------- K2: SE gate ----------------
__global__ __launch_bounds__(256) void k_gate(const float* __restrict__ avgp,
                                              const float* __restrict__ maxp,
                                              const float* __restrict__ w1,
                                              const float* __restrict__ w2,
                                              float* __restrict__ gate) {
    int b = blockIdx.x, t = threadIdx.x;
    __shared__ float sa[CCH], sx[CCH], sh[32];
    sa[t] = avgp[b * CCH + t];
    sx[t] = maxp[b * CCH + t];
    __syncthreads();
    if (t < 32) {
        int r = t & 15;
        const float* src = (t < 16) ? sa : sx;
        float h = 0.f;
        for (int c = 0; c < CCH; ++c) h += w1[r * CCH + c] * src[c];
        sh[t] = fmaxf(h, 0.f);
    }
    __syncthreads();
    float g = 0.f;
#pragma unroll
    for (int r = 0; r < RR; ++r) g += w2[t * RR + r] * (sh[r] + sh[16 + r]);
    gate[b * CCH + t] = 1.f / (1.f + __expf(-g));
}

// ---------------- K-wprep: pack [vw;qw;kw] -> Wb bf16 [288][256] ----------------
__global__ __launch_bounds__(256) void k_wprep(const float* __restrict__ vw,
                                               const float* __restrict__ qw,
                                               const float* __restrict__ kw,
                                               unsigned short* __restrict__ Wb) {
    int idx = blockIdx.x * 256 + threadIdx.x;   // 288*256 = 73728
    int m = idx >> 8, c = idx & 255;
    float v;
    if (m < 256) v = vw[idx];
    else if (m < 272) v = qw[(m - 256) * 256 + c];
    else v = kw[(m - 272) * 256 + c];
    Wb[idx] = f2bf(v);
}

// ---------------- K-proj: fused q,k,v projections via bf16 MFMA ----------------
// vB written in CHUNKED layout: vB[b][jc][c][jo], jc = global j-chunk (j>>3), jo = j&7,
// with the within-64 column permutation col = (n&15)*4 + ((n>>4)&3) baked in, matching
// k_attn's P column order. Stores go through an LDS bounce -> 1KB coalesced segments.
__global__ __launch_bounds__(256) void k_proj(const float* __restrict__ x,
                                              const float* __restrict__ gate,
                                              const unsigned short* __restrict__ Wb,
                                              const float* __restrict__ vb,
                                              const float* __restrict__ qb,
                                              const float* __restrict__ kb,
                                              unsigned short* __restrict__ qT,
                                              unsigned short* __restrict__ kT,
                                              unsigned short* __restrict__ vB) {
    int b = blockIdx.x & 7;              // XCD swizzle: batch <-> XCD
    int n0 = (blockIdx.x >> 3) << 6;
    int t = threadIdx.x;
    int w = t >> 6, l = t & 63, quad = l >> 4, ln = l & 15;

    __shared__ __align__(16) unsigned short xs_t[64][72];   // [n_local][c_local] bf16
    __shared__ __align__(16) unsigned short vtile[256 * 72]; // [m][col] bf16, stride 72
    __shared__ float qk_s[32][66];   // q rows 0..15, k rows 16..31 (fp32)

    const f32x4 zf = {0.f, 0.f, 0.f, 0.f};
    f32x4 acc[18];
#pragma unroll
    for (int mt = 0; mt < 18; ++mt) acc[mt] = zf;

    for (int cc = 0; cc < 4; ++cc) {
        __syncthreads();
#pragma unroll
        for (int it = 0; it < 4; ++it) {
            int idx = it * 256 + t;
            int cl = idx >> 4, nq = idx & 15;
            int c = cc * 64 + cl;
            float g = gate[b * CCH + c];
            float4 v = *(const float4*)(x + (((size_t)(b * CCH + c)) << 12) + n0 + nq * 4);
            xs_t[nq * 4 + 0][cl] = f2bf(v.x * g);
            xs_t[nq * 4 + 1][cl] = f2bf(v.y * g);
            xs_t[nq * 4 + 2][cl] = f2bf(v.z * g);
            xs_t[nq * 4 + 3][cl] = f2bf(v.w * g);
        }
        __syncthreads();

        short8 bfrag[2];
#pragma unroll
        for (int kc = 0; kc < 2; ++kc)
            bfrag[kc] = *(const short8*)&xs_t[w * 16 + ln][kc * 32 + quad * 8];

#pragma unroll
        for (int mt = 0; mt < 18; ++mt) {
#pragma unroll
            for (int kc = 0; kc < 2; ++kc) {
                short8 af = *(const short8*)(Wb + ((size_t)(mt * 16 + ln)) * 256 + cc * 64 + kc * 32 + quad * 8);
                acc[mt] = __builtin_amdgcn_mfma_f32_16x16x32_bf16(af, bfrag[kc], acc[mt], 0, 0, 0);
            }
        }
    }

    // v rows -> vtile[m][col], col = ln*4 + w  (since n_local = w*16+ln)
#pragma unroll
    for (int mt = 0; mt < 16; ++mt) {
#pragma unroll
        for (int r = 0; r < 4; ++r) {
            int m = mt * 16 + quad * 4 + r;
            vtile[m * 72 + ln * 4 + w] = f2bf(acc[mt][r] + vb[m]);
        }
    }
    // q/k -> LDS for transpose
#pragma unroll
    for (int r = 0; r < 4; ++r) {
        qk_s[quad * 4 + r][w * 16 + ln] = acc[16][r];
        qk_s[16 + quad * 4 + r][w * 16 + ln] = acc[17][r];
    }
    __syncthreads();

    // stream vtile -> vB chunks: thread t = c; 8 x 16B stores, 1KB coalesced segments
    {
        unsigned short* vBp = vB + (((size_t)b) << 20);
        int c = t;
#pragma unroll
        for (int Q = 0; Q < 8; ++Q) {
            short8 v8 = *(const short8*)(vtile + c * 72 + Q * 8);
            *(short8*)(vBp + ((size_t)((((n0 >> 3) + Q) << 8) + c) << 3)) = v8;
        }
    }
    if (t < 128) {
        int isK = t >> 6;
        int n = t & 63;
        const float* bias = isK ? kb : qb;
        unsigned u32[8];
#pragma unroll
        for (int j = 0; j < 8; ++j) {
            unsigned lo = f2bf(qk_s[isK * 16 + 2 * j][n] + bias[2 * j]);
            unsigned hi = f2bf(qk_s[isK * 16 + 2 * j + 1][n] + bias[2 * j + 1]);
            u32[j] = lo | (hi << 16);
        }
        unsigned short* dst = (isK ? kT : qT) + ((size_t)(b * HWN + n0 + n)) * RR;
        uint4 d0 = {u32[0], u32[1], u32[2], u32[3]};
        uint4 d1 = {u32[4], u32[5], u32[6], u32[7]};
        ((uint4*)dst)[0] = d0;
        ((uint4*)dst)[1] = d1;
    }
}

// ---------------- K-attn: MFMA flash attention ----------------
// Block (b XCD-swizzled, 64 i), 4 waves. j-tile 64, single barrier/step, P dbuf.
// V in chunked layout -> A-frag load = 4x256B contiguous segments. P stored as packed
// b64 in permuted column order (col = ln*4+jn) matching vB chunks. V/K for step n+1
// issued right AFTER barrier(n) -> drained at barrier(n+1), a full step later.
__global__ __launch_bounds__(256) void k_attn(const unsigned short* __restrict__ qT,
                                              const unsigned short* __restrict__ kT,
                                              const unsigned short* __restrict__ vB,
                                              const float* __restrict__ x,
                                              const float* __restrict__ gate,
                                              const float* __restrict__ gamma,
                                              float* __restrict__ out) {
    int b = blockIdx.x & 7;
    int i0 = ((blockIdx.x >> 3) & 63) << 6;
    int t = threadIdx.x;
    int w = t >> 6, l = t & 63;
    int quad = l >> 4, ln = l & 15;

    __shared__ __align__(16) unsigned short p_lds[2][64 * PSTR];
    __shared__ float l_s[64];

    const short8 zs = {0, 0, 0, 0, 0, 0, 0, 0};
    const f32x4 zf = {0.f, 0.f, 0.f, 0.f};

    short8 aq = zs;
    if (quad < 2)
        aq = *(const short8*)(qT + (((size_t)(b * HWN + i0 + w * 16 + ln)) << 4) + (quad << 3));

    f32x4 acc[4][4];
#pragma unroll
    for (int cs = 0; cs < 4; ++cs)
#pragma unroll
        for (int is = 0; is < 4; ++is) acc[cs][is] = zf;
    float lpart[4] = {0.f, 0.f, 0.f, 0.f};

    const float c1 = 1.44269504f;      // log2(e)
    const float c0 = -11.5415603f;     // -8*log2(e): fixed shift, cancels in p/l

    // vB chunk base for this batch & wave's c-range offset folded into cs*16+ln later
    const unsigned short* vbase = vB + (((size_t)b) << 20) + ((size_t)(w * 64) << 3);
    const unsigned short* kbase = kT + (((size_t)b * HWN)) * RR;

    short8 bkA[4], bkB[4], avA[8], avB[8];
#pragma unroll
    for (int jn = 0; jn < 4; ++jn) { bkA[jn] = zs; bkB[jn] = zs; }

    auto load_av = [&](short8 (&av)[8], int j0) {
#pragma unroll
        for (int ks = 0; ks < 2; ++ks)
#pragma unroll
            for (int cs = 0; cs < 4; ++cs) {
                int jc = (j0 >> 3) + ks * 4 + quad;
                av[ks * 4 + cs] = *(const short8*)(vbase + ((size_t)((jc << 8) + cs * 16 + ln) << 3));
            }
    };
    auto load_bk = [&](short8 (&bk)[4], int j0) {
        if (quad < 2) {
#pragma unroll
            for (int jn = 0; jn < 4; ++jn)
                bk[jn] = *(const short8*)(kbase + (((size_t)(j0 + jn * 16 + ln)) << 4) + (quad << 3));
        }
    };
    auto sstep = [&](short8 (&bk)[4], unsigned short* pbuf) {
        f32x4 sf[4];
#pragma unroll
        for (int jn = 0; jn < 4; ++jn)
            sf[jn] = __builtin_amdgcn_mfma_f32_16x16x32_bf16(aq, bk[jn], zf, 0, 0, 0);
#pragma unroll
        for (int r = 0; r < 4; ++r) {
            float p0 = exp2f(fmaf(sf[0][r], c1, c0));
            float p1 = exp2f(fmaf(sf[1][r], c1, c0));
            float p2 = exp2f(fmaf(sf[2][r], c1, c0));
            float p3 = exp2f(fmaf(sf[3][r], c1, c0));
            lpart[r] += (p0 + p1) + (p2 + p3);
            uint2 pk;
            pk.x = (bfr(p0) >> 16) | (bfr(p1) & 0xFFFF0000u);
            pk.y = (bfr(p2) >> 16) | (bfr(p3) & 0xFFFF0000u);
            *(uint2*)(pbuf + (w * 16 + quad * 4 + r) * PSTR + ln * 4) = pk;
        }
    };
    auto pvstep = [&](short8 (&av)[8], const unsigned short* pbuf) {
        short8 bp[4];
#pragma unroll
        for (int is = 0; is < 4; ++is)
            bp[is] = *(const short8*)(pbuf + (is * 16 + ln) * PSTR + quad * 8);
#pragma unroll
        for (int cs = 0; cs < 4; ++cs)
#pragma unroll
            for (int is = 0; is < 4; ++is)
                acc[cs][is] = __builtin_amdgcn_mfma_f32_16x16x32_bf16(av[cs], bp[is], acc[cs][is], 0, 0, 0);
#pragma unroll
        for (int is = 0; is < 4; ++is)
            bp[is] = *(const short8*)(pbuf + (is * 16 + ln) * PSTR + 32 + quad * 8);
#pragma unroll
        for (int cs = 0; cs < 4; ++cs)
#pragma unroll
            for (int is = 0; is < 4; ++is)
                acc[cs][is] = __builtin_amdgcn_mfma_f32_16x16x32_bf16(av[4 + cs], bp[is], acc[cs][is], 0, 0, 0);
    };

    load_bk(bkA, 0);
    load_av(avA, 0);

    for (int jt2 = 0; jt2 < 32; ++jt2) {
        int j0e = jt2 << 7;
        // even step: uses A-set, P buffer 0
        sstep(bkA, &p_lds[0][0]);
        __syncthreads();
        load_bk(bkB, j0e + 64);          // drained at NEXT barrier (full step later)
        load_av(avB, j0e + 64);
        pvstep(avA, &p_lds[0][0]);

        // odd step: uses B-set, P buffer 1
        sstep(bkB, &p_lds[1][0]);
        __syncthreads();
        int j0n = (jt2 < 31) ? (j0e + 128) : 0;   // clamp on last iter (loads discarded)
        load_bk(bkA, j0n);
        load_av(avA, j0n);
        pvstep(avB, &p_lds[1][0]);
    }

    // l: butterfly over the 16 lanes of each quad
#pragma unroll
    for (int r = 0; r < 4; ++r) {
        float v = lpart[r];
        v += __shfl_xor(v, 1, 64);
        v += __shfl_xor(v, 2, 64);
        v += __shfl_xor(v, 4, 64);
        v += __shfl_xor(v, 8, 64);
        if (ln == 0) l_s[w * 16 + quad * 4 + r] = v;
    }
    __syncthreads();

    float g = gamma[0];
    float rinv[4];
#pragma unroll
    for (int is = 0; is < 4; ++is) rinv[is] = g / l_s[is * 16 + ln];

    // epilogue: out = gamma*o/l + x*gate
#pragma unroll
    for (int cs = 0; cs < 4; ++cs) {
#pragma unroll
        for (int r = 0; r < 4; ++r) {
            int c = w * 64 + cs * 16 + quad * 4 + r;
            float gc = gate[b * CCH + c];
            size_t rowoff = (((size_t)(b * CCH + c)) << 12) + i0;
            float* po = out + rowoff;
            const float* px = x + rowoff;
#pragma unroll
            for (int is = 0; is < 4; ++is) {
                int idx = is * 16 + ln;
                po[idx] = acc[cs][is][r] * rinv[is] + px[idx] * gc;
            }
        }
    }
}

extern "C" void kernel_launch(void* const* d_in, const int* in_sizes, int n_in,
                              void* d_out, int out_size, void* d_ws, size_t ws_size,
                              hipStream_t stream) {
    const float* x = (const float*)d_in[0];
    const float* w1 = (const float*)d_in[1];
    const float* w2 = (const float*)d_in[2];
    const float* qw = (const float*)d_in[3];
    const float* qb = (const float*)d_in[4];
    const float* kw = (const float*)d_in[5];
    const float* kb = (const float*)d_in[6];
    const float* vw = (const float*)d_in[7];
    const float* vb = (const float*)d_in[8];
    const float* gamma = (const float*)d_in[9];
    float* out = (float*)d_out;
    char* ws = (char*)d_ws;

    float* avgp = (float*)(ws);                        // 8 KB
    float* maxp = (float*)(ws + 8192);                 // 8 KB
    float* gate = (float*)(ws + 16384);                // 8 KB
    unsigned short* Wb = (unsigned short*)(ws + 24576);               // [288][256] bf16
    unsigned short* qT = (unsigned short*)(ws + 24576 + 147456);      // 1 MB [b][n][16]
    unsigned short* kT = (unsigned short*)(ws + 24576 + 147456 + 1048576);
    unsigned short* vB = (unsigned short*)(ws + 24576 + 147456 + 2097152);  // 16.8 MB chunked

    k_pool<<<2048, 256, 0, stream>>>(x, avgp, maxp);
    k_wprep<<<288, 256, 0, stream>>>(vw, qw, kw, Wb);
    k_gate<<<8, 256, 0, stream>>>(avgp, maxp, w1, w2, gate);
    k_proj<<<512, 256, 0, stream>>>(x, gate, Wb, vb, qb, kb, qT, kT, vB);
    k_attn<<<512, 256, 0, stream>>>(qT, kT, vB, x, gate, gamma, out);
}

// Round 6
// 285.683 us; speedup vs baseline: 1.3848x; 1.2460x over previous
//
#include <hip/hip_runtime.h>
#include <hip/hip_bf16.h>
#include <math.h>

#define BB 8
#define CCH 256
#define HWN 4096
#define RR 16
#define PSTR 68   // p_lds ushort row stride (136B): conflict-free measured (R5: SQ_LDS_BANK_CONFLICT=0)

typedef __attribute__((ext_vector_type(8))) short short8;   // 8 bf16 = K=32 MFMA A/B frag
typedef __attribute__((ext_vector_type(4))) float f32x4;    // MFMA C/D frag

static __device__ __forceinline__ unsigned short f2bf(float x) {
    union { float f; unsigned u; } v; v.f = x;
    return (unsigned short)((v.u + 0x8000u) >> 16);   // round-half-up bf16
}
static __device__ __forceinline__ unsigned bfr(float x) {   // bits + rounding offset
    union { float f; unsigned u; } v; v.f = x;
    return v.u + 0x8000u;
}

// ---------------- K1: avg+max pool over spatial, per (b,c) ----------------
__global__ __launch_bounds__(256) void k_pool(const float* __restrict__ x,
                                              float* __restrict__ avgp,
                                              float* __restrict__ maxp) {
    int bc = blockIdx.x;
    const float4* p = (const float4*)(x + (size_t)bc * HWN);
    int t = threadIdx.x;
    float s = 0.f, m = -INFINITY;
#pragma unroll
    for (int i = 0; i < 4; ++i) {
        float4 v = p[t + 256 * i];
        s += v.x + v.y + v.z + v.w;
        m = fmaxf(m, fmaxf(fmaxf(v.x, v.y), fmaxf(v.z, v.w)));
    }
    for (int off = 32; off; off >>= 1) {
        s += __shfl_down(s, off);
        m = fmaxf(m, __shfl_down(m, off));
    }
    __shared__ float ss[4], sm[4];
    int wid = t >> 6;
    if ((t & 63) == 0) { ss[wid] = s; sm[wid] = m; }
    __syncthreads();
    if (t == 0) {
        float S = ss[0] + ss[1] + ss[2] + ss[3];
        float M = fmaxf(fmaxf(sm[0], sm[1]), fmaxf(sm[2], sm[3]));
        avgp[bc] = S * (1.f / (float)HWN);
        maxp[bc] = M;
    }
}

// ---------------- K2: SE gate ----------------
__global__ __launch_bounds__(256) void k_gate(const float* __restrict__ avgp,
                                              const float* __restrict__ maxp,
                                              const float* __restrict__ w1,
                                              const float* __restrict__ w2,
                                              float* __restrict__ gate) {
    int b = blockIdx.x, t = threadIdx.x;
    __shared__ float sa[CCH], sx[CCH], sh[32];
    sa[t] = avgp[b * CCH + t];
    sx[t] = maxp[b * CCH + t];
    __syncthreads();
    if (t < 32) {
        int r = t & 15;
        const float* src = (t < 16) ? sa : sx;
        float h = 0.f;
        for (int c = 0; c < CCH; ++c) h += w1[r * CCH + c] * src[c];
        sh[t] = fmaxf(h, 0.f);
    }
    __syncthreads();
    float g = 0.f;
#pragma unroll
    for (int r = 0; r < RR; ++r) g += w2[t * RR + r] * (sh[r] + sh[16 + r]);
    gate[b * CCH + t] = 1.f / (1.f + __expf(-g));
}

// ---------------- K-wprep: pack [vw;qw;kw] -> Wb bf16 [288][256] ----------------
__global__ __launch_bounds__(256) void k_wprep(const float* __restrict__ vw,
                                               const float* __restrict__ qw,
                                               const float* __restrict__ kw,
                                               unsigned short* __restrict__ Wb) {
    int idx = blockIdx.x * 256 + threadIdx.x;   // 288*256 = 73728
    int m = idx >> 8, c = idx & 255;
    float v;
    if (m < 256) v = vw[idx];
    else if (m < 272) v = qw[(m - 256) * 256 + c];
    else v = kw[(m - 272) * 256 + c];
    Wb[idx] = f2bf(v);
}

// ---------------- K-proj: fused q,k,v projections via bf16 MFMA ----------------
// vB written in CHUNKED layout: vB[b][jc][c][jo], jc = global j-chunk (j>>3), jo = j&7,
// with the within-64 column permutation col = (n&15)*4 + ((n>>4)&3) baked in, matching
// k_attn's P column order. Stores go through an LDS bounce -> 1KB coalesced segments.
__global__ __launch_bounds__(256) void k_proj(const float* __restrict__ x,
                                              const float* __restrict__ gate,
                                              const unsigned short* __restrict__ Wb,
                                              const float* __restrict__ vb,
                                              const float* __restrict__ qb,
                                              const float* __restrict__ kb,
                                              unsigned short* __restrict__ qT,
                                              unsigned short* __restrict__ kT,
                                              unsigned short* __restrict__ vB) {
    int b = blockIdx.x & 7;              // XCD swizzle: batch <-> XCD
    int n0 = (blockIdx.x >> 3) << 6;
    int t = threadIdx.x;
    int w = t >> 6, l = t & 63, quad = l >> 4, ln = l & 15;

    __shared__ __align__(16) unsigned short xs_t[64][72];   // [n_local][c_local] bf16
    __shared__ __align__(16) unsigned short vtile[256 * 72]; // [m][col] bf16, stride 72
    __shared__ float qk_s[32][66];   // q rows 0..15, k rows 16..31 (fp32)

    const f32x4 zf = {0.f, 0.f, 0.f, 0.f};
    f32x4 acc[18];
#pragma unroll
    for (int mt = 0; mt < 18; ++mt) acc[mt] = zf;

    for (int cc = 0; cc < 4; ++cc) {
        __syncthreads();
#pragma unroll
        for (int it = 0; it < 4; ++it) {
            int idx = it * 256 + t;
            int cl = idx >> 4, nq = idx & 15;
            int c = cc * 64 + cl;
            float g = gate[b * CCH + c];
            float4 v = *(const float4*)(x + (((size_t)(b * CCH + c)) << 12) + n0 + nq * 4);
            xs_t[nq * 4 + 0][cl] = f2bf(v.x * g);
            xs_t[nq * 4 + 1][cl] = f2bf(v.y * g);
            xs_t[nq * 4 + 2][cl] = f2bf(v.z * g);
            xs_t[nq * 4 + 3][cl] = f2bf(v.w * g);
        }
        __syncthreads();

        short8 bfrag[2];
#pragma unroll
        for (int kc = 0; kc < 2; ++kc)
            bfrag[kc] = *(const short8*)&xs_t[w * 16 + ln][kc * 32 + quad * 8];

#pragma unroll
        for (int mt = 0; mt < 18; ++mt) {
#pragma unroll
            for (int kc = 0; kc < 2; ++kc) {
                short8 af = *(const short8*)(Wb + ((size_t)(mt * 16 + ln)) * 256 + cc * 64 + kc * 32 + quad * 8);
                acc[mt] = __builtin_amdgcn_mfma_f32_16x16x32_bf16(af, bfrag[kc], acc[mt], 0, 0, 0);
            }
        }
    }

    // v rows -> vtile[m][col], col = ln*4 + w  (since n_local = w*16+ln)
#pragma unroll
    for (int mt = 0; mt < 16; ++mt) {
#pragma unroll
        for (int r = 0; r < 4; ++r) {
            int m = mt * 16 + quad * 4 + r;
            vtile[m * 72 + ln * 4 + w] = f2bf(acc[mt][r] + vb[m]);
        }
    }
    // q/k -> LDS for transpose
#pragma unroll
    for (int r = 0; r < 4; ++r) {
        qk_s[quad * 4 + r][w * 16 + ln] = acc[16][r];
        qk_s[16 + quad * 4 + r][w * 16 + ln] = acc[17][r];
    }
    __syncthreads();

    // stream vtile -> vB chunks: thread t = c; 8 x 16B stores, 1KB coalesced segments
    {
        unsigned short* vBp = vB + (((size_t)b) << 20);
        int c = t;
#pragma unroll
        for (int Q = 0; Q < 8; ++Q) {
            short8 v8 = *(const short8*)(vtile + c * 72 + Q * 8);
            *(short8*)(vBp + ((size_t)((((n0 >> 3) + Q) << 8) + c) << 3)) = v8;
        }
    }
    if (t < 128) {
        int isK = t >> 6;
        int n = t & 63;
        const float* bias = isK ? kb : qb;
        unsigned u32[8];
#pragma unroll
        for (int j = 0; j < 8; ++j) {
            unsigned lo = f2bf(qk_s[isK * 16 + 2 * j][n] + bias[2 * j]);
            unsigned hi = f2bf(qk_s[isK * 16 + 2 * j + 1][n] + bias[2 * j + 1]);
            u32[j] = lo | (hi << 16);
        }
        unsigned short* dst = (isK ? kT : qT) + ((size_t)(b * HWN + n0 + n)) * RR;
        uint4 d0 = {u32[0], u32[1], u32[2], u32[3]};
        uint4 d1 = {u32[4], u32[5], u32[6], u32[7]};
        ((uint4*)dst)[0] = d0;
        ((uint4*)dst)[1] = d1;
    }
}

// ---------------- K-attn: MFMA flash attention ----------------
// Block (b XCD-swizzled, 64 i), 4 waves, j-tile 64, 1 barrier/step, P dbuf.
// OCCUPANCY IS THE BINDING CONSTRAINT (R5 post-mortem): register V-dbuf pushed total
// regs past 256 -> 1 wave/SIMD (Occupancy 11.8%). This version: V SINGLE-buffered
// (loaded right after pvstep consumes it; drained at next barrier, gap=sstep~200cy),
// K double-buffered (16 regs; next-step K issued right after barrier, covered by
// pvstep ~300cy). __launch_bounds__(256,2) pins allocation <=256 regs -> 2 waves/SIMD.
__global__ __launch_bounds__(256, 2) void k_attn(const unsigned short* __restrict__ qT,
                                                 const unsigned short* __restrict__ kT,
                                                 const unsigned short* __restrict__ vB,
                                                 const float* __restrict__ x,
                                                 const float* __restrict__ gate,
                                                 const float* __restrict__ gamma,
                                                 float* __restrict__ out) {
    int b = blockIdx.x & 7;
    int i0 = ((blockIdx.x >> 3) & 63) << 6;
    int t = threadIdx.x;
    int w = t >> 6, l = t & 63;
    int quad = l >> 4, ln = l & 15;

    __shared__ __align__(16) unsigned short p_lds[2][64 * PSTR];
    __shared__ float l_s[64];

    const short8 zs = {0, 0, 0, 0, 0, 0, 0, 0};
    const f32x4 zf = {0.f, 0.f, 0.f, 0.f};

    short8 aq = zs;
    if (quad < 2)
        aq = *(const short8*)(qT + (((size_t)(b * HWN + i0 + w * 16 + ln)) << 4) + (quad << 3));

    f32x4 acc[4][4];
#pragma unroll
    for (int cs = 0; cs < 4; ++cs)
#pragma unroll
        for (int is = 0; is < 4; ++is) acc[cs][is] = zf;
    float lpart[4] = {0.f, 0.f, 0.f, 0.f};

    const float c1 = 1.44269504f;      // log2(e)
    const float c0 = -11.5415603f;     // -8*log2(e): fixed shift, cancels in p/l

    const unsigned short* vbase = vB + (((size_t)b) << 20) + ((size_t)(w * 64) << 3);
    const unsigned short* kbase = kT + (((size_t)b * HWN)) * RR;

    short8 av[8];                 // V A-frags, SINGLE buffer (occupancy)
    short8 bkA[4], bkB[4];        // K B-frags, double buffer
#pragma unroll
    for (int jn = 0; jn < 4; ++jn) { bkA[jn] = zs; bkB[jn] = zs; }

    auto load_av = [&](int j0) {
#pragma unroll
        for (int ks = 0; ks < 2; ++ks)
#pragma unroll
            for (int cs = 0; cs < 4; ++cs) {
                int jc = (j0 >> 3) + ks * 4 + quad;
                av[ks * 4 + cs] = *(const short8*)(vbase + ((size_t)((jc << 8) + cs * 16 + ln) << 3));
            }
    };
    auto load_bk = [&](short8 (&bk)[4], int j0) {
        if (quad < 2) {
#pragma unroll
            for (int jn = 0; jn < 4; ++jn)
                bk[jn] = *(const short8*)(kbase + (((size_t)(j0 + jn * 16 + ln)) << 4) + (quad << 3));
        }
    };
    auto sstep = [&](short8 (&bk)[4], unsigned short* pbuf) {
        f32x4 sf[4];
#pragma unroll
        for (int jn = 0; jn < 4; ++jn)
            sf[jn] = __builtin_amdgcn_mfma_f32_16x16x32_bf16(aq, bk[jn], zf, 0, 0, 0);
#pragma unroll
        for (int r = 0; r < 4; ++r) {
            float p0 = exp2f(fmaf(sf[0][r], c1, c0));
            float p1 = exp2f(fmaf(sf[1][r], c1, c0));
            float p2 = exp2f(fmaf(sf[2][r], c1, c0));
            float p3 = exp2f(fmaf(sf[3][r], c1, c0));
            lpart[r] += (p0 + p1) + (p2 + p3);
            uint2 pk;
            pk.x = (bfr(p0) >> 16) | (bfr(p1) & 0xFFFF0000u);
            pk.y = (bfr(p2) >> 16) | (bfr(p3) & 0xFFFF0000u);
            *(uint2*)(pbuf + (w * 16 + quad * 4 + r) * PSTR + ln * 4) = pk;
        }
    };
    auto pvstep = [&](const unsigned short* pbuf) {
        short8 bp[4];
#pragma unroll
        for (int is = 0; is < 4; ++is)
            bp[is] = *(const short8*)(pbuf + (is * 16 + ln) * PSTR + quad * 8);
#pragma unroll
        for (int cs = 0; cs < 4; ++cs)
#pragma unroll
            for (int is = 0; is < 4; ++is)
                acc[cs][is] = __builtin_amdgcn_mfma_f32_16x16x32_bf16(av[cs], bp[is], acc[cs][is], 0, 0, 0);
#pragma unroll
        for (int is = 0; is < 4; ++is)
            bp[is] = *(const short8*)(pbuf + (is * 16 + ln) * PSTR + 32 + quad * 8);
#pragma unroll
        for (int cs = 0; cs < 4; ++cs)
#pragma unroll
            for (int is = 0; is < 4; ++is)
                acc[cs][is] = __builtin_amdgcn_mfma_f32_16x16x32_bf16(av[4 + cs], bp[is], acc[cs][is], 0, 0, 0);
    };

    load_bk(bkA, 0);
    load_av(0);

    for (int jt2 = 0; jt2 < 32; ++jt2) {
        int j0 = jt2 << 7;
        // even step (uses bkA, P buffer 0)
        sstep(bkA, &p_lds[0][0]);
        __syncthreads();
        load_bk(bkB, j0 + 64);     // next K: latency covered by pvstep below
        pvstep(&p_lds[0][0]);      // consumes av
        load_av(j0 + 64);          // next V: drained at next barrier (after sstep)

        // odd step (uses bkB, P buffer 1)
        int j0n = (jt2 < 31) ? (j0 + 128) : 0;   // clamp on last iter (loads discarded)
        sstep(bkB, &p_lds[1][0]);
        __syncthreads();
        load_bk(bkA, j0n);
        pvstep(&p_lds[1][0]);
        load_av(j0n);
    }

    // l: butterfly over the 16 lanes of each quad
#pragma unroll
    for (int r = 0; r < 4; ++r) {
        float v = lpart[r];
        v += __shfl_xor(v, 1, 64);
        v += __shfl_xor(v, 2, 64);
        v += __shfl_xor(v, 4, 64);
        v += __shfl_xor(v, 8, 64);
        if (ln == 0) l_s[w * 16 + quad * 4 + r] = v;
    }
    __syncthreads();

    float g = gamma[0];
    float rinv[4];
#pragma unroll
    for (int is = 0; is < 4; ++is) rinv[is] = g / l_s[is * 16 + ln];

    // epilogue: out = gamma*o/l + x*gate
#pragma unroll
    for (int cs = 0; cs < 4; ++cs) {
#pragma unroll
        for (int r = 0; r < 4; ++r) {
            int c = w * 64 + cs * 16 + quad * 4 + r;
            float gc = gate[b * CCH + c];
            size_t rowoff = (((size_t)(b * CCH + c)) << 12) + i0;
            float* po = out + rowoff;
            const float* px = x + rowoff;
#pragma unroll
            for (int is = 0; is < 4; ++is) {
                int idx = is * 16 + ln;
                po[idx] = acc[cs][is][r] * rinv[is] + px[idx] * gc;
            }
        }
    }
}

extern "C" void kernel_launch(void* const* d_in, const int* in_sizes, int n_in,
                              void* d_out, int out_size, void* d_ws, size_t ws_size,
                              hipStream_t stream) {
    const float* x = (const float*)d_in[0];
    const float* w1 = (const float*)d_in[1];
    const float* w2 = (const float*)d_in[2];
    const float* qw = (const float*)d_in[3];
    const float* qb = (const float*)d_in[4];
    const float* kw = (const float*)d_in[5];
    const float* kb = (const float*)d_in[6];
    const float* vw = (const float*)d_in[7];
    const float* vb = (const float*)d_in[8];
    const float* gamma = (const float*)d_in[9];
    float* out = (float*)d_out;
    char* ws = (char*)d_ws;

    float* avgp = (float*)(ws);                        // 8 KB
    float* maxp = (float*)(ws + 8192);                 // 8 KB
    float* gate = (float*)(ws + 16384);                // 8 KB
    unsigned short* Wb = (unsigned short*)(ws + 24576);               // [288][256] bf16
    unsigned short* qT = (unsigned short*)(ws + 24576 + 147456);      // 1 MB [b][n][16]
    unsigned short* kT = (unsigned short*)(ws + 24576 + 147456 + 1048576);
    unsigned short* vB = (unsigned short*)(ws + 24576 + 147456 + 2097152);  // 16.8 MB chunked

    k_pool<<<2048, 256, 0, stream>>>(x, avgp, maxp);
    k_wprep<<<288, 256, 0, stream>>>(vw, qw, kw, Wb);
    k_gate<<<8, 256, 0, stream>>>(avgp, maxp, w1, w2, gate);
    k_proj<<<512, 256, 0, stream>>>(x, gate, Wb, vb, qb, kb, qT, kT, vB);
    k_attn<<<512, 256, 0, stream>>>(qT, kT, vB, x, gate, gamma, out);
}

// Round 7
// 257.724 us; speedup vs baseline: 1.5350x; 1.1085x over previous
//
#include <hip/hip_runtime.h>
#include <hip/hip_bf16.h>
#include <math.h>

#define BB 8
#define CCH 256
#define HWN 4096
#define RR 16
#define PSTR 72   // p_lds ushort row stride (144B): 16B-aligned b128 rows, min-cycle bank pattern

typedef __attribute__((ext_vector_type(8))) short short8;   // 8 bf16 = K=32 MFMA A/B frag (4 VGPRs)
typedef __attribute__((ext_vector_type(4))) float f32x4;    // MFMA C/D frag

static __device__ __forceinline__ unsigned short f2bf(float x) {
    union { float f; unsigned u; } v; v.f = x;
    return (unsigned short)((v.u + 0x8000u) >> 16);   // round-half-up bf16
}
static __device__ __forceinline__ unsigned bfr(float x) {   // bits + rounding offset
    union { float f; unsigned u; } v; v.f = x;
    return v.u + 0x8000u;
}

// ---------------- K1: avg+max pool over spatial, per (b,c) ----------------
__global__ __launch_bounds__(256) void k_pool(const float* __restrict__ x,
                                              float* __restrict__ avgp,
                                              float* __restrict__ maxp) {
    int bc = blockIdx.x;
    const float4* p = (const float4*)(x + (size_t)bc * HWN);
    int t = threadIdx.x;
    float s = 0.f, m = -INFINITY;
#pragma unroll
    for (int i = 0; i < 4; ++i) {
        float4 v = p[t + 256 * i];
        s += v.x + v.y + v.z + v.w;
        m = fmaxf(m, fmaxf(fmaxf(v.x, v.y), fmaxf(v.z, v.w)));
    }
    for (int off = 32; off; off >>= 1) {
        s += __shfl_down(s, off);
        m = fmaxf(m, __shfl_down(m, off));
    }
    __shared__ float ss[4], sm[4];
    int wid = t >> 6;
    if ((t & 63) == 0) { ss[wid] = s; sm[wid] = m; }
    __syncthreads();
    if (t == 0) {
        float S = ss[0] + ss[1] + ss[2] + ss[3];
        float M = fmaxf(fmaxf(sm[0], sm[1]), fmaxf(sm[2], sm[3]));
        avgp[bc] = S * (1.f / (float)HWN);
        maxp[bc] = M;
    }
}

// ---------------- K2: SE gate ----------------
__global__ __launch_bounds__(256) void k_gate(const float* __restrict__ avgp,
                                              const float* __restrict__ maxp,
                                              const float* __restrict__ w1,
                                              const float* __restrict__ w2,
                                              float* __restrict__ gate) {
    int b = blockIdx.x, t = threadIdx.x;
    __shared__ float sa[CCH], sx[CCH], sh[32];
    sa[t] = avgp[b * CCH + t];
    sx[t] = maxp[b * CCH + t];
    __syncthreads();
    if (t < 32) {
        int r = t & 15;
        const float* src = (t < 16) ? sa : sx;
        float h = 0.f;
        for (int c = 0; c < CCH; ++c) h += w1[r * CCH + c] * src[c];
        sh[t] = fmaxf(h, 0.f);
    }
    __syncthreads();
    float g = 0.f;
#pragma unroll
    for (int r = 0; r < RR; ++r) g += w2[t * RR + r] * (sh[r] + sh[16 + r]);
    gate[b * CCH + t] = 1.f / (1.f + __expf(-g));
}

// ---------------- K-wprep: pack [vw;qw;kw] -> Wb bf16 [288][256] ----------------
__global__ __launch_bounds__(256) void k_wprep(const float* __restrict__ vw,
                                               const float* __restrict__ qw,
                                               const float* __restrict__ kw,
                                               unsigned short* __restrict__ Wb) {
    int idx = blockIdx.x * 256 + threadIdx.x;   // 288*256 = 73728
    int m = idx >> 8, c = idx & 255;
    float v;
    if (m < 256) v = vw[idx];
    else if (m < 272) v = qw[(m - 256) * 256 + c];
    else v = kw[(m - 272) * 256 + c];
    Wb[idx] = f2bf(v);
}

// ---------------- K-proj: fused q,k,v projections via bf16 MFMA ----------------
// vB in CHUNKED layout, NATURAL j order: vB[b][jc][c][jo], jc = j>>3, jo = j&7
// (R7: S^T trick makes P's column order natural, so the permutation is gone).
__global__ __launch_bounds__(256) void k_proj(const float* __restrict__ x,
                                              const float* __restrict__ gate,
                                              const unsigned short* __restrict__ Wb,
                                              const float* __restrict__ vb,
                                              const float* __restrict__ qb,
                                              const float* __restrict__ kb,
                                              unsigned short* __restrict__ qT,
                                              unsigned short* __restrict__ kT,
                                              unsigned short* __restrict__ vB) {
    int b = blockIdx.x & 7;              // XCD swizzle: batch <-> XCD
    int n0 = (blockIdx.x >> 3) << 6;
    int t = threadIdx.x;
    int w = t >> 6, l = t & 63, quad = l >> 4, ln = l & 15;

    __shared__ __align__(16) unsigned short xs_t[64][72];    // [n_local][c_local] bf16
    __shared__ __align__(16) unsigned short vtile[256 * 72]; // [m][n_local] bf16, stride 72
    __shared__ float qk_s[32][66];   // q rows 0..15, k rows 16..31 (fp32)

    const f32x4 zf = {0.f, 0.f, 0.f, 0.f};
    f32x4 acc[18];
#pragma unroll
    for (int mt = 0; mt < 18; ++mt) acc[mt] = zf;

    for (int cc = 0; cc < 4; ++cc) {
        __syncthreads();
#pragma unroll
        for (int it = 0; it < 4; ++it) {
            int idx = it * 256 + t;
            int cl = idx >> 4, nq = idx & 15;
            int c = cc * 64 + cl;
            float g = gate[b * CCH + c];
            float4 v = *(const float4*)(x + (((size_t)(b * CCH + c)) << 12) + n0 + nq * 4);
            xs_t[nq * 4 + 0][cl] = f2bf(v.x * g);
            xs_t[nq * 4 + 1][cl] = f2bf(v.y * g);
            xs_t[nq * 4 + 2][cl] = f2bf(v.z * g);
            xs_t[nq * 4 + 3][cl] = f2bf(v.w * g);
        }
        __syncthreads();

        short8 bfrag[2];
#pragma unroll
        for (int kc = 0; kc < 2; ++kc)
            bfrag[kc] = *(const short8*)&xs_t[w * 16 + ln][kc * 32 + quad * 8];

#pragma unroll
        for (int mt = 0; mt < 18; ++mt) {
#pragma unroll
            for (int kc = 0; kc < 2; ++kc) {
                short8 af = *(const short8*)(Wb + ((size_t)(mt * 16 + ln)) * 256 + cc * 64 + kc * 32 + quad * 8);
                acc[mt] = __builtin_amdgcn_mfma_f32_16x16x32_bf16(af, bfrag[kc], acc[mt], 0, 0, 0);
            }
        }
    }

    // v rows -> vtile[m][n_local] (natural column order)
#pragma unroll
    for (int mt = 0; mt < 16; ++mt) {
#pragma unroll
        for (int r = 0; r < 4; ++r) {
            int m = mt * 16 + quad * 4 + r;
            vtile[m * 72 + w * 16 + ln] = f2bf(acc[mt][r] + vb[m]);
        }
    }
    // q/k -> LDS for transpose
#pragma unroll
    for (int r = 0; r < 4; ++r) {
        qk_s[quad * 4 + r][w * 16 + ln] = acc[16][r];
        qk_s[16 + quad * 4 + r][w * 16 + ln] = acc[17][r];
    }
    __syncthreads();

    // stream vtile -> vB chunks: thread t = c; 8 x 16B stores, 1KB coalesced segments
    {
        unsigned short* vBp = vB + (((size_t)b) << 20);
        int c = t;
#pragma unroll
        for (int Q = 0; Q < 8; ++Q) {
            short8 v8 = *(const short8*)(vtile + c * 72 + Q * 8);
            *(short8*)(vBp + ((size_t)((((n0 >> 3) + Q) << 8) + c) << 3)) = v8;
        }
    }
    if (t < 128) {
        int isK = t >> 6;
        int n = t & 63;
        const float* bias = isK ? kb : qb;
        unsigned u32[8];
#pragma unroll
        for (int j = 0; j < 8; ++j) {
            unsigned lo = f2bf(qk_s[isK * 16 + 2 * j][n] + bias[2 * j]);
            unsigned hi = f2bf(qk_s[isK * 16 + 2 * j + 1][n] + bias[2 * j + 1]);
            u32[j] = lo | (hi << 16);
        }
        unsigned short* dst = (isK ? kT : qT) + ((size_t)(b * HWN + n0 + n)) * RR;
        uint4 d0 = {u32[0], u32[1], u32[2], u32[3]};
        uint4 d1 = {u32[4], u32[5], u32[6], u32[7]};
        ((uint4*)dst)[0] = d0;
        ((uint4*)dst)[1] = d1;
    }
}

// ---------------- K-attn: MFMA flash attention, 8-wave blocks, 4 waves/SIMD ----------------
// R7: parallelism was the ceiling (R6: grid=2 blocks/CU, 2 waves/SIMD, 50% idle).
// Block = (b XCD-swizzled, 32-i tile), 512 threads = 8 waves, grid 8x128=1024.
// Wave w: S^T tile (isub=w&1 -> 16 i, jsub=w>>1 -> 16 j of the 64-j step) via ONE MFMA
// with A=K, B=Q (S^T!): C row=j, col=i -> lane packs its 4 j's for one i as uint2 ->
// P lands [i][j] NATURAL -> PV B-frags are contiguous b128. PV: wave owns c=w*32..+32,
// 8 MFMAs. V+K double-buffered in regs, next-step loads issued right after the barrier
// (full-step gap before drain). ~110 VGPRs -> __launch_bounds__(512,4) = 4 waves/SIMD.
__global__ __launch_bounds__(512, 4) void k_attn(const unsigned short* __restrict__ qT,
                                                 const unsigned short* __restrict__ kT,
                                                 const unsigned short* __restrict__ vB,
                                                 const float* __restrict__ x,
                                                 const float* __restrict__ gate,
                                                 const float* __restrict__ gamma,
                                                 float* __restrict__ out) {
    int b = blockIdx.x & 7;
    int i0 = (blockIdx.x >> 3) << 5;     // 32-i tile
    int t = threadIdx.x;
    int w = t >> 6, l = t & 63;
    int quad = l >> 4, ln = l & 15;
    int isub = w & 1, jsub = w >> 1;
    int c0 = w * 32;

    __shared__ __align__(16) unsigned short p_lds[2][32 * PSTR];
    __shared__ float l_s[4][36];

    const short8 zs = {0, 0, 0, 0, 0, 0, 0, 0};
    const f32x4 zf = {0.f, 0.f, 0.f, 0.f};

    // persistent Q B-frag: B[k=d=quad*8+kk][n=i=ln] (quads 2,3 zero-pad d 16..31)
    short8 bq = zs;
    if (quad < 2)
        bq = *(const short8*)(qT + (((size_t)(b * HWN + i0 + isub * 16 + ln)) << 4) + (quad << 3));

    f32x4 acc[2][2];   // [cs][is]
#pragma unroll
    for (int cs = 0; cs < 2; ++cs)
#pragma unroll
        for (int is = 0; is < 2; ++is) acc[cs][is] = zf;
    float lsum = 0.f;

    const float c1 = 1.44269504f;      // log2(e)
    const float c0e = -11.5415603f;    // -8*log2(e): fixed shift, cancels in p/l

    const unsigned short* vbase = vB + (((size_t)b) << 20) + ((size_t)c0 << 3);
    const unsigned short* kbase = kT + ((size_t)(b * HWN)) * RR;

    short8 akA = zs, akB = zs;          // K A-frag dbuf: A[m=j=ln][k=d]
    short8 avA[4], avB[4];              // V A-frag dbuf: [ks*2+cs]

    auto load_ak = [&](short8& ak, int j0) {
        if (quad < 2)
            ak = *(const short8*)(kbase + (((size_t)(j0 + jsub * 16 + ln)) << 4) + (quad << 3));
    };
    auto load_av = [&](short8 (&av)[4], int j0) {
#pragma unroll
        for (int ks = 0; ks < 2; ++ks)
#pragma unroll
            for (int cs = 0; cs < 2; ++cs) {
                int jc = (j0 >> 3) + ks * 4 + quad;
                av[ks * 2 + cs] = *(const short8*)(vbase + ((size_t)(((jc << 8) + cs * 16 + ln)) << 3));
            }
    };

    load_ak(akA, 0);
    load_av(avA, 0);

    auto step = [&](short8& akC, short8 (&avC)[4], short8& akN, short8 (&avN)[4],
                    unsigned short* pbuf, int j0n, bool pf) {
        // S^T: C[row = j_local = quad*4+r][col = i_local = ln]
        f32x4 sf = __builtin_amdgcn_mfma_f32_16x16x32_bf16(akC, bq, zf, 0, 0, 0);

        float p0 = exp2f(fmaf(sf[0], c1, c0e));
        float p1 = exp2f(fmaf(sf[1], c1, c0e));
        float p2 = exp2f(fmaf(sf[2], c1, c0e));
        float p3 = exp2f(fmaf(sf[3], c1, c0e));
        lsum += (p0 + p1) + (p2 + p3);
        uint2 pk;
        pk.x = (bfr(p0) >> 16) | (bfr(p1) & 0xFFFF0000u);
        pk.y = (bfr(p2) >> 16) | (bfr(p3) & 0xFFFF0000u);
        // P[i = isub*16+ln][j = jsub*16 + quad*4 .. +4]  (natural j order)
        *(uint2*)(pbuf + (isub * 16 + ln) * PSTR + jsub * 16 + quad * 4) = pk;

        __syncthreads();   // P(buf) visible; prev-step prefetches drained

        // next-step V/K issued HERE: drained at next barrier, a full step later
        if (pf) { load_ak(akN, j0n); load_av(avN, j0n); }

        // PV: A = V[c][j], B = P[j][i] (b128 contiguous rows)
#pragma unroll
        for (int ks = 0; ks < 2; ++ks) {
            short8 bp[2];
#pragma unroll
            for (int is = 0; is < 2; ++is)
                bp[is] = *(const short8*)(pbuf + (is * 16 + ln) * PSTR + ks * 32 + quad * 8);
#pragma unroll
            for (int cs = 0; cs < 2; ++cs)
#pragma unroll
                for (int is = 0; is < 2; ++is)
                    acc[cs][is] = __builtin_amdgcn_mfma_f32_16x16x32_bf16(avC[ks * 2 + cs], bp[is], acc[cs][is], 0, 0, 0);
        }
    };

    for (int jt2 = 0; jt2 < 32; ++jt2) {
        int j0 = jt2 << 7;
        step(akA, avA, akB, avB, &p_lds[0][0], j0 + 64, true);
        step(akB, avB, akA, avA, &p_lds[1][0], (jt2 < 31) ? (j0 + 128) : 0, jt2 < 31);
    }

    // l reduction: lane's lsum covers its 4 j's (one i = isub*16+ln per lane-column)
    lsum += __shfl_xor(lsum, 16, 64);
    lsum += __shfl_xor(lsum, 32, 64);
    if (l < 16) l_s[jsub][isub * 16 + l] = lsum;
    __syncthreads();

    float g = gamma[0];
    float rinv[2];
#pragma unroll
    for (int is = 0; is < 2; ++is) {
        int i = is * 16 + ln;
        float lf = (l_s[0][i] + l_s[1][i]) + (l_s[2][i] + l_s[3][i]);
        rinv[is] = g / lf;
    }

    // epilogue: out = gamma*o/l + x*gate
#pragma unroll
    for (int cs = 0; cs < 2; ++cs) {
#pragma unroll
        for (int r = 0; r < 4; ++r) {
            int c = c0 + cs * 16 + quad * 4 + r;
            float gc = gate[b * CCH + c];
            size_t rowoff = (((size_t)(b * CCH + c)) << 12) + i0;
            float* po = out + rowoff;
            const float* px = x + rowoff;
#pragma unroll
            for (int is = 0; is < 2; ++is) {
                int idx = is * 16 + ln;
                po[idx] = acc[cs][is][r] * rinv[is] + px[idx] * gc;
            }
        }
    }
}

extern "C" void kernel_launch(void* const* d_in, const int* in_sizes, int n_in,
                              void* d_out, int out_size, void* d_ws, size_t ws_size,
                              hipStream_t stream) {
    const float* x = (const float*)d_in[0];
    const float* w1 = (const float*)d_in[1];
    const float* w2 = (const float*)d_in[2];
    const float* qw = (const float*)d_in[3];
    const float* qb = (const float*)d_in[4];
    const float* kw = (const float*)d_in[5];
    const float* kb = (const float*)d_in[6];
    const float* vw = (const float*)d_in[7];
    const float* vb = (const float*)d_in[8];
    const float* gamma = (const float*)d_in[9];
    float* out = (float*)d_out;
    char* ws = (char*)d_ws;

    float* avgp = (float*)(ws);                        // 8 KB
    float* maxp = (float*)(ws + 8192);                 // 8 KB
    float* gate = (float*)(ws + 16384);                // 8 KB
    unsigned short* Wb = (unsigned short*)(ws + 24576);               // [288][256] bf16
    unsigned short* qT = (unsigned short*)(ws + 24576 + 147456);      // 1 MB [b][n][16]
    unsigned short* kT = (unsigned short*)(ws + 24576 + 147456 + 1048576);
    unsigned short* vB = (unsigned short*)(ws + 24576 + 147456 + 2097152);  // 16.8 MB chunked

    k_pool<<<2048, 256, 0, stream>>>(x, avgp, maxp);
    k_wprep<<<288, 256, 0, stream>>>(vw, qw, kw, Wb);
    k_gate<<<8, 256, 0, stream>>>(avgp, maxp, w1, w2, gate);
    k_proj<<<512, 256, 0, stream>>>(x, gate, Wb, vb, qb, kb, qT, kT, vB);
    k_attn<<<1024, 512, 0, stream>>>(qT, kT, vB, x, gate, gamma, out);
}